// Round 8
// baseline (196.275 us; speedup 1.0000x reference)
//
#include <hip/hip_runtime.h>
#include <hip/hip_bf16.h>

// B=2, T=2048, C=1024, H=16, D=64, M = B*T = 4096
#define TT 2048
#define MM 4096
#define KS_LD 72   // attn LDS stride (shorts): 36 dwords, gcd(36,32)=4 -> ~2-way aliasing (free)

typedef __attribute__((ext_vector_type(8))) short bf16x8;
typedef __attribute__((ext_vector_type(4))) float f32x4;

__device__ inline short f2bf(float f){
  union { float f; unsigned u; } x; x.f = f;
  unsigned r = x.u + 0x7FFFu + ((x.u >> 16) & 1u);
  return (short)(r >> 16);
}

// async global->LDS, 16B per lane; LDS dest must be wave-uniform base + lane*16
__device__ inline void async16(const void* g, void* l){
  __builtin_amdgcn_global_load_lds((const __attribute__((address_space(1))) void*)g,
                                   (__attribute__((address_space(3))) void*)l, 16, 0, 0);
}

// ---------------- fused fp32 -> bf16 convert (x + 4 weights, one launch) ----------------
__global__ void cvt_all(const float* __restrict__ x,
                        const float* __restrict__ Wq, const float* __restrict__ Wk,
                        const float* __restrict__ Wv, const float* __restrict__ Wp,
                        short* __restrict__ xb, short* __restrict__ Wqb, short* __restrict__ Wkb,
                        short* __restrict__ Wvb, short* __restrict__ Wpb){
  int b = blockIdx.x;
  const float* in; short* out; int base;
  if (b < 4096)      { in = x;  out = xb;  base = b; }
  else if (b < 5120) { in = Wq; out = Wqb; base = b - 4096; }
  else if (b < 6144) { in = Wk; out = Wkb; base = b - 5120; }
  else if (b < 7168) { in = Wv; out = Wvb; base = b - 6144; }
  else               { in = Wp; out = Wpb; base = b - 7168; }
  int i = base * 256 + threadIdx.x;
  float4 v = ((const float4*)in)[i];
  short4 o;
  o.x = f2bf(v.x); o.y = f2bf(v.y); o.z = f2bf(v.z); o.w = f2bf(v.w);
  ((short4*)out)[i] = o;
}

// ---------------- GEMM core: 128x128 tile, BK=64 as two BK=32 panels, async staging ----------------
// Panels keep global_load_lds' contiguous-dest rule AND the conflict-free 32-short row stride.
// A [M,1024] bf16 row-major, Wm [1024,1024] bf16 row-major (N,K): C = A * Wm^T
__device__ inline void gemm_core(const short* __restrict__ A, const short* __restrict__ Wm,
                                 short* As, short* Bs, int m0, int n0,
                                 int tid, int wm, int wn, int quad, int lr,
                                 f32x4 acc[4][4])
{
  const int prow = tid >> 2, pcol = (tid & 3) << 3;   // chunk c=tid (rows 0..63) and c=tid+256 (rows 64..127)
  const short* Ap0 = A  + (size_t)(m0 + prow) * 1024 + pcol;
  const short* Ap1 = A  + (size_t)(m0 + prow + 64) * 1024 + pcol;
  const short* Bp0 = Wm + (size_t)(n0 + prow) * 1024 + pcol;
  const short* Bp1 = Wm + (size_t)(n0 + prow + 64) * 1024 + pcol;
  for (int kt = 0; kt < 16; ++kt){
    const int kk = kt * 64;
#pragma unroll
    for (int pn = 0; pn < 2; ++pn){     // panel pn covers cols kk+pn*32 .. +32
      async16(Ap0 + kk + pn*32, As + pn*4096 + (size_t)tid * 8);
      async16(Ap1 + kk + pn*32, As + pn*4096 + (size_t)(tid + 256) * 8);
      async16(Bp0 + kk + pn*32, Bs + pn*4096 + (size_t)tid * 8);
      async16(Bp1 + kk + pn*32, Bs + pn*4096 + (size_t)(tid + 256) * 8);
    }
    __syncthreads();   // drains vmcnt before any lane crosses
#pragma unroll
    for (int ks = 0; ks < 2; ++ks){
      bf16x8 aF[4], bF[4];
#pragma unroll
      for (int mt = 0; mt < 4; ++mt) aF[mt] = *(const bf16x8*)(As + ks*4096 + (wm*64 + mt*16 + lr)*32 + quad*8);
#pragma unroll
      for (int nt = 0; nt < 4; ++nt) bF[nt] = *(const bf16x8*)(Bs + ks*4096 + (wn*64 + nt*16 + lr)*32 + quad*8);
#pragma unroll
      for (int mt = 0; mt < 4; ++mt)
#pragma unroll
        for (int nt = 0; nt < 4; ++nt)
          acc[mt][nt] = __builtin_amdgcn_mfma_f32_16x16x32_bf16(aF[mt], bF[nt], acc[mt][nt], 0, 0, 0);
    }
    __syncthreads();   // frag reads done before next iter's loads overwrite
  }
}

// ---------------- QKV projection: Q,K as [B,H,T,D] (Q pre-scaled), V as [B,H,D,T] ----------------
__launch_bounds__(256, 3)
__global__ void gemm_qkv(const short* __restrict__ A,
                         const short* __restrict__ W0, const short* __restrict__ W1, const short* __restrict__ W2,
                         const float* __restrict__ b0, const float* __restrict__ b1, const float* __restrict__ b2,
                         short* __restrict__ Qo, short* __restrict__ Ko, short* __restrict__ Vt)
{
  // As/Bs = 2 panels x 4096 shorts each; epilogue overlays (needs <= 9216 shorts)
  __shared__ __align__(16) short smem[16384];
  short* As = smem;
  short* Bs = smem + 8192;
  const int z = blockIdx.z;
  const short* Wm   = (z == 0) ? W0 : ((z == 1) ? W1 : W2);
  const float* bias = (z == 0) ? b0 : ((z == 1) ? b1 : b2);
  const int tid = threadIdx.x;
  const int lane = tid & 63, wave = tid >> 6;
  const int wm = wave >> 1, wn = wave & 1;
  const int quad = lane >> 4, lr = lane & 15;
  const int m0 = blockIdx.y * 128, n0 = blockIdx.x * 128;

  f32x4 acc[4][4];
#pragma unroll
  for (int i = 0; i < 4; ++i)
#pragma unroll
    for (int j = 0; j < 4; ++j)
#pragma unroll
      for (int r = 0; r < 4; ++r) acc[i][j][r] = 0.f;

  gemm_core(A, Wm, As, Bs, m0, n0, tid, wm, wn, quad, lr, acc);

  const float qscale = 0.125f * 1.4426950408889634f;  // scale/sqrt(D) * log2(e) folded into Q
  const int bB = m0 >> 11, t0 = m0 & 2047;

  if (z == 2){
    // V: transpose in LDS -> coalesced [B,H,D,T] stores
#pragma unroll
    for (int nh = 0; nh < 2; ++nh){
      __syncthreads();
      if (wn == nh){
#pragma unroll
        for (int nt = 0; nt < 4; ++nt){
          int n = n0 + wn*64 + nt*16 + lr;
          float bv = bias[n];
          int n_l = nt*16 + lr;
#pragma unroll
          for (int mt = 0; mt < 4; ++mt)
#pragma unroll
            for (int r = 0; r < 4; ++r){
              int m_l = wm*64 + mt*16 + quad*4 + r;
              smem[n_l*136 + m_l] = f2bf(acc[mt][nt][r] + bv);
            }
        }
      }
      __syncthreads();
#pragma unroll
      for (int i = 0; i < 4; ++i){
        int c = tid + i*256;                   // 1024 chunks: 64 n-rows x 16 chunks of 8 shorts
        int rowN = c >> 4, ch = c & 15;
        int4 v = *(const int4*)(smem + rowN*136 + ch*8);
        int n = n0 + nh*64 + rowN;
        int hH = n >> 6, d = n & 63;
        *(int4*)(Vt + ((size_t)((bB<<4) + hH)*64 + d)*2048 + t0 + ch*8) = v;
      }
    }
    return;
  }

  // Q/K: stage [m][n] tile half-by-half in LDS (stride 72), then coalesced int4 row stores
  short* dst = (z == 0) ? Qo : Ko;
#pragma unroll
  for (int nh = 0; nh < 2; ++nh){
    __syncthreads();
    if (wn == nh){
#pragma unroll
      for (int nt = 0; nt < 4; ++nt){
        int n_l = nt*16 + lr;
        float bv = bias[n0 + nh*64 + n_l];
#pragma unroll
        for (int mt = 0; mt < 4; ++mt){
#pragma unroll
          for (int r = 0; r < 4; ++r){
            int m_l = wm*64 + mt*16 + quad*4 + r;
            float v = acc[mt][nt][r] + bv;
            if (z == 0) v *= qscale;
            smem[m_l*72 + n_l] = f2bf(v);
          }
        }
      }
    }
    __syncthreads();
    const int hH = (n0 + nh*64) >> 6;
    short* dhead = dst + (size_t)((bB<<4) + hH) * 2048 * 64;
#pragma unroll
    for (int i = 0; i < 4; ++i){
      int c = tid + i*256;                     // 1024 chunks: 128 m-rows x 8 chunks of 8 shorts
      int rowm = c >> 3, ch = (c & 7) << 3;
      int4 v = *(const int4*)(smem + rowm*72 + ch);
      *(int4*)(dhead + (size_t)(t0 + rowm)*64 + ch) = v;
    }
  }
}

// ---------------- output projection: 128x64 tiles, BK=64 two-panel ----------------
__launch_bounds__(256, 2)
__global__ void gemm_proj(const short* __restrict__ A, const short* __restrict__ Wm,
                          const float* __restrict__ bias, float* __restrict__ out)
{
  __shared__ __align__(16) short As[2*4096];
  __shared__ __align__(16) short Bs[2*2048];
  const int tid = threadIdx.x;
  const int lane = tid & 63, wave = tid >> 6;
  const int quad = lane >> 4, lr = lane & 15;
  const int m0 = blockIdx.y * 128, n0 = blockIdx.x * 64;

  const int prow = tid >> 2, pcol = (tid & 3) << 3;
  const short* Ap0 = A  + (size_t)(m0 + prow) * 1024 + pcol;
  const short* Ap1 = A  + (size_t)(m0 + prow + 64) * 1024 + pcol;
  const short* Bp0 = Wm + (size_t)(n0 + (tid >> 2)) * 1024 + pcol;   // 64 n-rows, 1 chunk/thread/panel

  f32x4 acc[2][4];
#pragma unroll
  for (int i = 0; i < 2; ++i)
#pragma unroll
    for (int j = 0; j < 4; ++j)
#pragma unroll
      for (int r = 0; r < 4; ++r) acc[i][j][r] = 0.f;

  for (int kt = 0; kt < 16; ++kt){
    const int kk = kt * 64;
#pragma unroll
    for (int pn = 0; pn < 2; ++pn){
      async16(Ap0 + kk + pn*32, As + pn*4096 + (size_t)tid * 8);
      async16(Ap1 + kk + pn*32, As + pn*4096 + (size_t)(tid + 256) * 8);
      async16(Bp0 + kk + pn*32, Bs + pn*2048 + (size_t)tid * 8);
    }
    __syncthreads();
#pragma unroll
    for (int ks = 0; ks < 2; ++ks){
      bf16x8 aF[2], bF[4];
#pragma unroll
      for (int mt = 0; mt < 2; ++mt) aF[mt] = *(const bf16x8*)(As + ks*4096 + (wave*32 + mt*16 + lr)*32 + quad*8);
#pragma unroll
      for (int nt = 0; nt < 4; ++nt) bF[nt] = *(const bf16x8*)(Bs + ks*2048 + (nt*16 + lr)*32 + quad*8);
#pragma unroll
      for (int mt = 0; mt < 2; ++mt)
#pragma unroll
        for (int nt = 0; nt < 4; ++nt)
          acc[mt][nt] = __builtin_amdgcn_mfma_f32_16x16x32_bf16(aF[mt], bF[nt], acc[mt][nt], 0, 0, 0);
    }
    __syncthreads();
  }

#pragma unroll
  for (int nt = 0; nt < 4; ++nt){
    int n = n0 + nt*16 + lr;
    float bv = bias[n];
#pragma unroll
    for (int mt = 0; mt < 2; ++mt){
      int mBase = m0 + wave*32 + mt*16 + quad*4;
#pragma unroll
      for (int r = 0; r < 4; ++r){
        int m = mBase + r;
        out[(size_t)m * 1024 + n] = acc[mt][nt][r] + bv;
      }
    }
  }
}

// ---------------- flash attention (causal): uniform work via additive KV-split ----------------
// Q (pre-scaled by log2e/8), K: [B*H, T, 64] bf16 ; Vt: [B*H, 64, T] bf16 ; AO: [B*T, 1024] bf16
// No-max exp2 softmax => partials are ADDITIVE across KV chunks. Grid 1280 = 32 heads x 40 slots:
//   slot<32:  qt = 31-(slot>>1) in [16,31], chunk = slot&1 halves [0,qt+1); atomicAdd fp32 partials.
//   slot>=32: paired light tiles qt = {p, 15-p}, 17 tiles, direct bf16 AO write.
// Every block does 8..17 KV tiles (vs 1..32 before); 5 blocks/CU resident, one round.
__launch_bounds__(256, 5)
__global__ void attn_kernel(const short* __restrict__ Q, const short* __restrict__ K,
                            const short* __restrict__ Vt, short* __restrict__ AO,
                            float* __restrict__ OAcc, float* __restrict__ lAcc)
{
  __shared__ __align__(16) short Ks[64*KS_LD];
  __shared__ __align__(16) short Vs[64*KS_LD];
  __shared__ __align__(16) short Ps[4*16*KS_LD];
  const int tid = threadIdx.x, lane = tid & 63, wave = tid >> 6;
  const int quad = lane >> 4, lr = lane & 15;
  const int bid = blockIdx.x;
  const int slot = bid >> 5;
  const int hb = bid & 31;             // head interleave for XCD/L2 spread
  const int bidx = hb >> 4, h = hb & 15;
  const short* Qh = Q  + (size_t)hb * TT * 64;
  const short* Kh = K  + (size_t)hb * TT * 64;
  const short* Vh = Vt + (size_t)hb * 64 * TT;
  short* Pw = Ps + wave * 16 * KS_LD;

  int qts[2], k0s[2], k1s[2], np;
  bool partial;
  if (slot < 32){
    int qt = 31 - (slot >> 1);
    int half = (qt + 1) >> 1;
    int c = slot & 1;
    qts[0] = qt; k0s[0] = c ? half : 0; k1s[0] = c ? (qt + 1) : half;
    np = 1; partial = true;
  } else {
    int p = slot - 32;
    qts[0] = p;      k0s[0] = 0; k1s[0] = p + 1;
    qts[1] = 15 - p; k0s[1] = 0; k1s[1] = 16 - p;
    np = 2; partial = false;
  }

  const short one_bf = (short)0x3F80;
  const bf16x8 onesf = { one_bf, one_bf, one_bf, one_bf, one_bf, one_bf, one_bf, one_bf };
  const int srow = tid >> 3, scol = (tid & 7) << 3;   // staging: chunk c = tid and tid+256 (row+32)

  for (int ph = 0; ph < np; ++ph){
    const int qt = qts[ph];
    const int q0 = qt * 64;
    const int wq = q0 + wave * 16;     // this wave's 16 q-rows

    bf16x8 qf[2];
#pragma unroll
    for (int ks = 0; ks < 2; ++ks)
      qf[ks] = *(const bf16x8*)(Qh + (size_t)(wq + lr) * 64 + ks*32 + quad*8);

    f32x4 acc_o[4], l_acc;
#pragma unroll
    for (int r = 0; r < 4; ++r) l_acc[r] = 0.f;
#pragma unroll
    for (int dt = 0; dt < 4; ++dt)
#pragma unroll
      for (int r = 0; r < 4; ++r) acc_o[dt][r] = 0.f;

    for (int kv = k0s[ph]; kv < k1s[ph]; ++kv){
      const int kv0 = kv * 64;
      __syncthreads();                 // previous tile's consumers done
#pragma unroll
      for (int s = 0; s < 2; ++s){
        *(int4*)(Ks + (srow + s*32) * KS_LD + scol) = *(const int4*)(Kh + (size_t)(kv0 + srow + s*32) * 64 + scol);
        *(int4*)(Vs + (srow + s*32) * KS_LD + scol) = *(const int4*)(Vh + (size_t)(srow + s*32) * TT + kv0 + scol);
      }
      __syncthreads();
      if (kv0 > wq + 15) continue;     // this wave's rows fully masked (tile above diagonal)

      f32x4 s4[4];
#pragma unroll
      for (int nt = 0; nt < 4; ++nt)
#pragma unroll
        for (int r = 0; r < 4; ++r) s4[nt][r] = 0.f;
#pragma unroll
      for (int nt = 0; nt < 4; ++nt)
#pragma unroll
        for (int ks = 0; ks < 2; ++ks){
          bf16x8 kf = *(const bf16x8*)(Ks + (nt*16 + lr)*KS_LD + ks*32 + quad*8);
          s4[nt] = __builtin_amdgcn_mfma_f32_16x16x32_bf16(qf[ks], kf, s4[nt], 0, 0, 0);
        }

      // P = exp2(S); diagonal tile only when kv0 == q0 (chunk0 never contains it)
      const bool need_mask = (kv0 == q0);
      const int prow = quad * 4;
      const int qg = wq + prow;
#pragma unroll
      for (int nt = 0; nt < 4; ++nt){
        const int key = kv0 + nt*16 + lr;
        float pv[4];
#pragma unroll
        for (int r = 0; r < 4; ++r){
          float v = exp2f(s4[nt][r]);
          if (need_mask && key > qg + r) v = 0.f;
          pv[r] = v;
        }
#pragma unroll
        for (int rp = 0; rp < 2; ++rp){
          __hip_bfloat162 h2 = __float22bfloat162_rn(make_float2(pv[2*rp], pv[2*rp+1]));
          unsigned u = *(unsigned*)&h2;
          Pw[(prow + 2*rp    )*KS_LD + nt*16 + lr] = (short)(u & 0xffffu);
          Pw[(prow + 2*rp + 1)*KS_LD + nt*16 + lr] = (short)(u >> 16);
        }
      }
      // wave-private Ps: lgkmcnt ordering only, no barrier

#pragma unroll
      for (int ks = 0; ks < 2; ++ks){
        bf16x8 pf = *(const bf16x8*)(Pw + lr*KS_LD + ks*32 + quad*8);
        l_acc = __builtin_amdgcn_mfma_f32_16x16x32_bf16(pf, onesf, l_acc, 0, 0, 0);
#pragma unroll
        for (int dt = 0; dt < 4; ++dt){
          bf16x8 vf = *(const bf16x8*)(Vs + (dt*16 + lr)*KS_LD + ks*32 + quad*8);
          acc_o[dt] = __builtin_amdgcn_mfma_f32_16x16x32_bf16(pf, vf, acc_o[dt], 0, 0, 0);
        }
      }
    }

    if (!partial){
      // light tiles: finalize and write bf16 AO directly
      float inv[4];
#pragma unroll
      for (int r = 0; r < 4; ++r) inv[r] = __builtin_amdgcn_rcpf(l_acc[r]);
#pragma unroll
      for (int dt = 0; dt < 4; ++dt){
        int d = dt*16 + lr;
#pragma unroll
        for (int r = 0; r < 4; ++r){
          int qg = wq + quad*4 + r;
          AO[(size_t)(bidx*2048 + qg)*1024 + h*64 + d] = f2bf(acc_o[dt][r] * inv[r]);
        }
      }
    } else {
      // heavy tiles: additive fp32 partials (device-scope atomics)
      float* Ob = OAcc + (size_t)((hb*16 + (qt - 16))*64) * 64;
#pragma unroll
      for (int dt = 0; dt < 4; ++dt){
        int d = dt*16 + lr;
#pragma unroll
        for (int r = 0; r < 4; ++r){
          int row = wave*16 + quad*4 + r;
          atomicAdd(Ob + (size_t)row*64 + d, acc_o[dt][r]);
        }
      }
      if (lr == 0){
        float* lb = lAcc + (hb*16 + (qt - 16))*64;
#pragma unroll
        for (int r = 0; r < 4; ++r)
          atomicAdd(lb + wave*16 + quad*4 + r, l_acc[r]);
      }
    }
  }
}

// ---------------- combine partials for qt>=16: AO = OAcc / lAcc (bf16) ----------------
__global__ void attn_combine(const float* __restrict__ OAcc, const float* __restrict__ lAcc,
                             short* __restrict__ AO)
{
  const int blk = blockIdx.x;          // 512 = 32 hb x 16 qti
  const int hb = blk & 31, qti = blk >> 5;
  const int bidx = hb >> 4, h = hb & 15;
  const int tid = threadIdx.x;
  const int row = tid >> 2, dseg = (tid & 3) << 4;
  const float* Op = OAcc + ((size_t)((hb*16 + qti)*64 + row)) * 64 + dseg;
  const float inv = __builtin_amdgcn_rcpf(lAcc[(hb*16 + qti)*64 + row]);
  float4 v0 = ((const float4*)Op)[0], v1 = ((const float4*)Op)[1];
  float4 v2 = ((const float4*)Op)[2], v3 = ((const float4*)Op)[3];
  short o[16];
  o[0]=f2bf(v0.x*inv); o[1]=f2bf(v0.y*inv); o[2]=f2bf(v0.z*inv); o[3]=f2bf(v0.w*inv);
  o[4]=f2bf(v1.x*inv); o[5]=f2bf(v1.y*inv); o[6]=f2bf(v1.z*inv); o[7]=f2bf(v1.w*inv);
  o[8]=f2bf(v2.x*inv); o[9]=f2bf(v2.y*inv); o[10]=f2bf(v2.z*inv); o[11]=f2bf(v2.w*inv);
  o[12]=f2bf(v3.x*inv); o[13]=f2bf(v3.y*inv); o[14]=f2bf(v3.z*inv); o[15]=f2bf(v3.w*inv);
  const int q = 1024 + qti*64 + row;   // qt = qti+16 -> q0 = 1024 + qti*64
  short* dst = AO + (size_t)(bidx*2048 + q)*1024 + h*64 + dseg;
  ((int4*)dst)[0] = *(const int4*)&o[0];
  ((int4*)dst)[1] = *(const int4*)&o[8];
}

extern "C" void kernel_launch(void* const* d_in, const int* in_sizes, int n_in,
                              void* d_out, int out_size, void* d_ws, size_t ws_size,
                              hipStream_t stream)
{
  const float* x  = (const float*)d_in[0];
  const float* Wq = (const float*)d_in[1];
  const float* bq = (const float*)d_in[2];
  const float* Wk = (const float*)d_in[3];
  const float* bk = (const float*)d_in[4];
  const float* Wv = (const float*)d_in[5];
  const float* bv = (const float*)d_in[6];
  const float* Wp = (const float*)d_in[7];
  const float* bp = (const float*)d_in[8];
  float* out = (float*)d_out;

  char* ws = (char*)d_ws;
  const size_t MB = 1024ull * 1024ull;
  const size_t KB = 1024ull;
  short* Qb   = (short*)(ws + 0);            // [B,H,T,D] bf16 (pre-scaled by log2e/8)
  short* Kb   = (short*)(ws + 8*MB);         // [B,H,T,D] bf16
  short* Vtb  = (short*)(ws + 16*MB);        // [B,H,D,T] bf16
  short* AOb  = (short*)(ws + 24*MB);        // [B*T, C] bf16 — ALIASES xb (qkv reads finish first)
  short* xb   = (short*)(ws + 24*MB);        // [M, C] bf16
  float* OAcc = (float*)(ws + 32*MB);        // [32 hb][16 qt][64 q][64 d] f32 partials, 8 MB
  float* lAcc = (float*)(ws + 40*MB);        // [32 hb][16 qt][64 q] f32, 128 KB
  short* Wqb  = (short*)(ws + 40*MB + 128*KB);
  short* Wkb  = (short*)(ws + 42*MB + 128*KB);
  short* Wvb  = (short*)(ws + 44*MB + 128*KB);
  short* Wpb  = (short*)(ws + 46*MB + 128*KB);

  hipMemsetAsync(ws + 32*MB, 0, 8*MB + 128*KB, stream);   // zero OAcc + lAcc (graph-safe)
  cvt_all<<<8192, 256, 0, stream>>>(x, Wq, Wk, Wv, Wp, xb, Wqb, Wkb, Wvb, Wpb);
  gemm_qkv<<<dim3(8, 32, 3), 256, 0, stream>>>(xb, Wqb, Wkb, Wvb, bq, bk, bv, Qb, Kb, Vtb);
  attn_kernel<<<1280, 256, 0, stream>>>(Qb, Kb, Vtb, AOb, OAcc, lAcc);
  attn_combine<<<512, 256, 0, stream>>>(OAcc, lAcc, AOb);
  gemm_proj<<<dim3(16, 32), 256, 0, stream>>>(AOb, Wpb, bp, out);
}

// Round 9
// 187.214 us; speedup vs baseline: 1.0484x; 1.0484x over previous
//
#include <hip/hip_runtime.h>
#include <hip/hip_bf16.h>

// B=2, T=2048, C=1024, H=16, D=64, M = B*T = 4096
#define TT 2048
#define MM 4096
#define KS_LD 72   // LDS stride (shorts): 36 dwords, gcd(36,32)=4 -> ~2-way aliasing on staging

typedef __attribute__((ext_vector_type(8))) short bf16x8;
typedef __attribute__((ext_vector_type(4))) float f32x4;

__device__ inline short f2bf(float f){
  union { float f; unsigned u; } x; x.f = f;
  unsigned r = x.u + 0x7FFFu + ((x.u >> 16) & 1u);
  return (short)(r >> 16);
}
__device__ inline int pk2bf(float a, float b){
  __hip_bfloat162 h2 = __float22bfloat162_rn(make_float2(a, b));
  return *(int*)&h2;
}

// async global->LDS, 16B per lane; LDS dest must be wave-uniform base + lane*16
__device__ inline void async16(const void* g, void* l){
  __builtin_amdgcn_global_load_lds((const __attribute__((address_space(1))) void*)g,
                                   (__attribute__((address_space(3))) void*)l, 16, 0, 0);
}

// ---------------- fused fp32 -> bf16 convert (x + 4 weights, one launch) ----------------
__global__ void cvt_all(const float* __restrict__ x,
                        const float* __restrict__ Wq, const float* __restrict__ Wk,
                        const float* __restrict__ Wv, const float* __restrict__ Wp,
                        short* __restrict__ xb, short* __restrict__ Wqb, short* __restrict__ Wkb,
                        short* __restrict__ Wvb, short* __restrict__ Wpb){
  int b = blockIdx.x;
  const float* in; short* out; int base;
  if (b < 4096)      { in = x;  out = xb;  base = b; }
  else if (b < 5120) { in = Wq; out = Wqb; base = b - 4096; }
  else if (b < 6144) { in = Wk; out = Wkb; base = b - 5120; }
  else if (b < 7168) { in = Wv; out = Wvb; base = b - 6144; }
  else               { in = Wp; out = Wpb; base = b - 7168; }
  int i = base * 256 + threadIdx.x;
  float4 v = ((const float4*)in)[i];
  short4 o;
  o.x = f2bf(v.x); o.y = f2bf(v.y); o.z = f2bf(v.z); o.w = f2bf(v.w);
  ((short4*)out)[i] = o;
}

// ---------------- GEMM core: 128x128 tile, BK=64 as two BK=32 panels, async staging ----------------
__device__ inline void gemm_core(const short* __restrict__ A, const short* __restrict__ Wm,
                                 short* As, short* Bs, int m0, int n0,
                                 int tid, int wm, int wn, int quad, int lr,
                                 f32x4 acc[4][4])
{
  const int prow = tid >> 2, pcol = (tid & 3) << 3;
  const short* Ap0 = A  + (size_t)(m0 + prow) * 1024 + pcol;
  const short* Ap1 = A  + (size_t)(m0 + prow + 64) * 1024 + pcol;
  const short* Bp0 = Wm + (size_t)(n0 + prow) * 1024 + pcol;
  const short* Bp1 = Wm + (size_t)(n0 + prow + 64) * 1024 + pcol;
  for (int kt = 0; kt < 16; ++kt){
    const int kk = kt * 64;
#pragma unroll
    for (int pn = 0; pn < 2; ++pn){
      async16(Ap0 + kk + pn*32, As + pn*4096 + (size_t)tid * 8);
      async16(Ap1 + kk + pn*32, As + pn*4096 + (size_t)(tid + 256) * 8);
      async16(Bp0 + kk + pn*32, Bs + pn*4096 + (size_t)tid * 8);
      async16(Bp1 + kk + pn*32, Bs + pn*4096 + (size_t)(tid + 256) * 8);
    }
    __syncthreads();
#pragma unroll
    for (int ks = 0; ks < 2; ++ks){
      bf16x8 aF[4], bF[4];
#pragma unroll
      for (int mt = 0; mt < 4; ++mt) aF[mt] = *(const bf16x8*)(As + ks*4096 + (wm*64 + mt*16 + lr)*32 + quad*8);
#pragma unroll
      for (int nt = 0; nt < 4; ++nt) bF[nt] = *(const bf16x8*)(Bs + ks*4096 + (wn*64 + nt*16 + lr)*32 + quad*8);
#pragma unroll
      for (int mt = 0; mt < 4; ++mt)
#pragma unroll
        for (int nt = 0; nt < 4; ++nt)
          acc[mt][nt] = __builtin_amdgcn_mfma_f32_16x16x32_bf16(aF[mt], bF[nt], acc[mt][nt], 0, 0, 0);
    }
    __syncthreads();
  }
}

// ---------------- QKV projection: Q,K as [B,H,T,D] (Q pre-scaled), V as [B,H,D,T] ----------------
__launch_bounds__(256, 3)
__global__ void gemm_qkv(const short* __restrict__ A,
                         const short* __restrict__ W0, const short* __restrict__ W1, const short* __restrict__ W2,
                         const float* __restrict__ b0, const float* __restrict__ b1, const float* __restrict__ b2,
                         short* __restrict__ Qo, short* __restrict__ Ko, short* __restrict__ Vt)
{
  __shared__ __align__(16) short smem[16384];
  short* As = smem;
  short* Bs = smem + 8192;
  const int z = blockIdx.z;
  const short* Wm   = (z == 0) ? W0 : ((z == 1) ? W1 : W2);
  const float* bias = (z == 0) ? b0 : ((z == 1) ? b1 : b2);
  const int tid = threadIdx.x;
  const int lane = tid & 63, wave = tid >> 6;
  const int wm = wave >> 1, wn = wave & 1;
  const int quad = lane >> 4, lr = lane & 15;
  const int m0 = blockIdx.y * 128, n0 = blockIdx.x * 128;

  f32x4 acc[4][4];
#pragma unroll
  for (int i = 0; i < 4; ++i)
#pragma unroll
    for (int j = 0; j < 4; ++j)
#pragma unroll
      for (int r = 0; r < 4; ++r) acc[i][j][r] = 0.f;

  gemm_core(A, Wm, As, Bs, m0, n0, tid, wm, wn, quad, lr, acc);

  const float qscale = 0.125f * 1.4426950408889634f;  // scale/sqrt(D) * log2(e) folded into Q
  const int bB = m0 >> 11, t0 = m0 & 2047;

  if (z == 2){
    // V: transpose in LDS -> coalesced [B,H,D,T] stores
#pragma unroll
    for (int nh = 0; nh < 2; ++nh){
      __syncthreads();
      if (wn == nh){
#pragma unroll
        for (int nt = 0; nt < 4; ++nt){
          int n = n0 + wn*64 + nt*16 + lr;
          float bv = bias[n];
          int n_l = nt*16 + lr;
#pragma unroll
          for (int mt = 0; mt < 4; ++mt)
#pragma unroll
            for (int r = 0; r < 4; ++r){
              int m_l = wm*64 + mt*16 + quad*4 + r;
              smem[n_l*136 + m_l] = f2bf(acc[mt][nt][r] + bv);
            }
        }
      }
      __syncthreads();
#pragma unroll
      for (int i = 0; i < 4; ++i){
        int c = tid + i*256;
        int rowN = c >> 4, ch = c & 15;
        int4 v = *(const int4*)(smem + rowN*136 + ch*8);
        int n = n0 + nh*64 + rowN;
        int hH = n >> 6, d = n & 63;
        *(int4*)(Vt + ((size_t)((bB<<4) + hH)*64 + d)*2048 + t0 + ch*8) = v;
      }
    }
    return;
  }

  // Q/K: stage [m][n] tile half-by-half in LDS (stride 72), then coalesced int4 row stores
  short* dst = (z == 0) ? Qo : Ko;
#pragma unroll
  for (int nh = 0; nh < 2; ++nh){
    __syncthreads();
    if (wn == nh){
#pragma unroll
      for (int nt = 0; nt < 4; ++nt){
        int n_l = nt*16 + lr;
        float bv = bias[n0 + nh*64 + n_l];
#pragma unroll
        for (int mt = 0; mt < 4; ++mt){
#pragma unroll
          for (int r = 0; r < 4; ++r){
            int m_l = wm*64 + mt*16 + quad*4 + r;
            float v = acc[mt][nt][r] + bv;
            if (z == 0) v *= qscale;
            smem[m_l*72 + n_l] = f2bf(v);
          }
        }
      }
    }
    __syncthreads();
    const int hH = (n0 + nh*64) >> 6;
    short* dhead = dst + (size_t)((bB<<4) + hH) * 2048 * 64;
#pragma unroll
    for (int i = 0; i < 4; ++i){
      int c = tid + i*256;
      int rowm = c >> 3, ch = (c & 7) << 3;
      int4 v = *(const int4*)(smem + rowm*72 + ch);
      *(int4*)(dhead + (size_t)(t0 + rowm)*64 + ch) = v;
    }
  }
}

// ---------------- output projection: 128x64 tiles, BK=64 two-panel ----------------
__launch_bounds__(256, 2)
__global__ void gemm_proj(const short* __restrict__ A, const short* __restrict__ Wm,
                          const float* __restrict__ bias, float* __restrict__ out)
{
  __shared__ __align__(16) short As[2*4096];
  __shared__ __align__(16) short Bs[2*2048];
  const int tid = threadIdx.x;
  const int lane = tid & 63, wave = tid >> 6;
  const int quad = lane >> 4, lr = lane & 15;
  const int m0 = blockIdx.y * 128, n0 = blockIdx.x * 64;

  const int prow = tid >> 2, pcol = (tid & 3) << 3;
  const short* Ap0 = A  + (size_t)(m0 + prow) * 1024 + pcol;
  const short* Ap1 = A  + (size_t)(m0 + prow + 64) * 1024 + pcol;
  const short* Bp0 = Wm + (size_t)(n0 + (tid >> 2)) * 1024 + pcol;

  f32x4 acc[2][4];
#pragma unroll
  for (int i = 0; i < 2; ++i)
#pragma unroll
    for (int j = 0; j < 4; ++j)
#pragma unroll
      for (int r = 0; r < 4; ++r) acc[i][j][r] = 0.f;

  for (int kt = 0; kt < 16; ++kt){
    const int kk = kt * 64;
#pragma unroll
    for (int pn = 0; pn < 2; ++pn){
      async16(Ap0 + kk + pn*32, As + pn*4096 + (size_t)tid * 8);
      async16(Ap1 + kk + pn*32, As + pn*4096 + (size_t)(tid + 256) * 8);
      async16(Bp0 + kk + pn*32, Bs + pn*2048 + (size_t)tid * 8);
    }
    __syncthreads();
#pragma unroll
    for (int ks = 0; ks < 2; ++ks){
      bf16x8 aF[2], bF[4];
#pragma unroll
      for (int mt = 0; mt < 2; ++mt) aF[mt] = *(const bf16x8*)(As + ks*4096 + (wave*32 + mt*16 + lr)*32 + quad*8);
#pragma unroll
      for (int nt = 0; nt < 4; ++nt) bF[nt] = *(const bf16x8*)(Bs + ks*2048 + (nt*16 + lr)*32 + quad*8);
#pragma unroll
      for (int mt = 0; mt < 2; ++mt)
#pragma unroll
        for (int nt = 0; nt < 4; ++nt)
          acc[mt][nt] = __builtin_amdgcn_mfma_f32_16x16x32_bf16(aF[mt], bF[nt], acc[mt][nt], 0, 0, 0);
    }
    __syncthreads();
  }

#pragma unroll
  for (int nt = 0; nt < 4; ++nt){
    int n = n0 + nt*16 + lr;
    float bv = bias[n];
#pragma unroll
    for (int mt = 0; mt < 2; ++mt){
      int mBase = m0 + wave*32 + mt*16 + quad*4;
#pragma unroll
      for (int r = 0; r < 4; ++r){
        int m = mBase + r;
        out[(size_t)m * 1024 + n] = acc[mt][nt][r] + bv;
      }
    }
  }
}

// ---------------- flash attention (causal): S^T formulation, vectorized P round-trip ----------------
// Q (pre-scaled by log2e/8), K: [B*H, T, 64] bf16 ; Vt: [B*H, 64, T] bf16 ; AO: [B*T, 1024] bf16
// Grid 1024 = 32 q-tiles(64 rows) x 32 heads, heavy-diagonal first, 4 blocks/CU, one round.
// S^T = mfma(K-frag, Q-frag) puts q in the lane dimension (col=lr) -> P^T packs along keys:
// 4 ds_write_b64 + 2 ds_read_b128 per tile (was 32 ds_write_u16 + 4 reads). PV computes
// O^T = mfma(V^T-frag, P^T-frag); epilogue transposes O^T via LDS into coalesced AO stores.
__launch_bounds__(256, 4)
__global__ void attn_kernel(const short* __restrict__ Q, const short* __restrict__ K,
                            const short* __restrict__ Vt, short* __restrict__ AO)
{
  __shared__ __align__(16) short Ks[64*KS_LD];
  __shared__ __align__(16) short Vs[64*KS_LD];
  __shared__ __align__(16) short Ps[4*16*KS_LD];   // per-wave P^T/O^T scratch: [16 q][64+8]
  const int tid = threadIdx.x, lane = tid & 63, wave = tid >> 6;
  const int quad = lane >> 4, lr = lane & 15;
  const int bid = blockIdx.x;
  const int qt = 31 - (bid >> 5);      // heavy (diagonal) q-tiles first
  const int hb = bid & 31;
  const int bidx = hb >> 4, h = hb & 15;
  const int q0 = qt * 64;
  const int wq = q0 + wave * 16;       // this wave's 16 q-rows
  const short* Qh = Q  + (size_t)hb * TT * 64;
  const short* Kh = K  + (size_t)hb * TT * 64;
  const short* Vh = Vt + (size_t)hb * 64 * TT;
  short* Pw = Ps + wave * 16 * KS_LD;

  // loop-invariant Q fragments (used as B-operand: B[k][n=lr=q] = Q[q][k], same lane mapping)
  bf16x8 qf[2];
#pragma unroll
  for (int ks = 0; ks < 2; ++ks)
    qf[ks] = *(const bf16x8*)(Qh + (size_t)(wq + lr) * 64 + ks*32 + quad*8);

  // O^T accumulators: acc_o[dt] holds O[d=16dt+4quad+r][q=lr]; l_acc regs all = l[q=lr]
  f32x4 acc_o[4], l_acc;
#pragma unroll
  for (int r = 0; r < 4; ++r) l_acc[r] = 0.f;
#pragma unroll
  for (int dt = 0; dt < 4; ++dt)
#pragma unroll
    for (int r = 0; r < 4; ++r) acc_o[dt][r] = 0.f;

  const short one_bf = (short)0x3F80;
  const bf16x8 onesf = { one_bf, one_bf, one_bf, one_bf, one_bf, one_bf, one_bf, one_bf };

  // staging geometry: 512 int4 per matrix per tile; chunk c = tid and tid+256 (row+32)
  const int srow = tid >> 3, scol = (tid & 7) << 3;

  const int nkv = qt + 1;
  for (int kv = 0; kv < nkv; ++kv){
    const int kv0 = kv * 64;
    __syncthreads();                       // previous tile's consumers done
#pragma unroll
    for (int s = 0; s < 2; ++s){
      *(int4*)(Ks + (srow + s*32) * KS_LD + scol) = *(const int4*)(Kh + (size_t)(kv0 + srow + s*32) * 64 + scol);
      *(int4*)(Vs + (srow + s*32) * KS_LD + scol) = *(const int4*)(Vh + (size_t)(srow + s*32) * TT + kv0 + scol);
    }
    __syncthreads();
    if (kv0 > wq + 15) continue;           // this wave's rows fully masked

    // S^T = K Q^T: C-layout col = q = lr, row = key = 16nt + 4quad + r
    f32x4 s4[4];
#pragma unroll
    for (int nt = 0; nt < 4; ++nt)
#pragma unroll
      for (int r = 0; r < 4; ++r) s4[nt][r] = 0.f;
#pragma unroll
    for (int nt = 0; nt < 4; ++nt)
#pragma unroll
      for (int ks = 0; ks < 2; ++ks){
        bf16x8 kf = *(const bf16x8*)(Ks + (nt*16 + lr)*KS_LD + ks*32 + quad*8);
        s4[nt] = __builtin_amdgcn_mfma_f32_16x16x32_bf16(kf, qf[ks], s4[nt], 0, 0, 0);
      }

    // P^T = exp2(S^T), mask key > q on the diagonal tile; pack 4 keys -> one b64 store per nt
    const bool need_mask = (kv == nkv - 1);
    const int qglob = wq + lr;
#pragma unroll
    for (int nt = 0; nt < 4; ++nt){
      const int keyb = kv0 + nt*16 + quad*4;
      float pv[4];
#pragma unroll
      for (int r = 0; r < 4; ++r){
        float v = exp2f(s4[nt][r]);
        if (need_mask && keyb + r > qglob) v = 0.f;
        pv[r] = v;
      }
      int2 w;
      w.x = pk2bf(pv[0], pv[1]);
      w.y = pk2bf(pv[2], pv[3]);
      *(int2*)(Pw + lr*KS_LD + nt*16 + quad*4) = w;
    }
    // wave-private Pw: lgkmcnt ordering only, no barrier

    // l += 1^T P^T ; O^T += V^T P^T   (B-frag = P^T rows q=lr, keys 32ks+8quad+j)
#pragma unroll
    for (int ks = 0; ks < 2; ++ks){
      bf16x8 ptf = *(const bf16x8*)(Pw + lr*KS_LD + ks*32 + quad*8);
      l_acc = __builtin_amdgcn_mfma_f32_16x16x32_bf16(onesf, ptf, l_acc, 0, 0, 0);
#pragma unroll
      for (int dt = 0; dt < 4; ++dt){
        bf16x8 vf = *(const bf16x8*)(Vs + (dt*16 + lr)*KS_LD + ks*32 + quad*8);
        acc_o[dt] = __builtin_amdgcn_mfma_f32_16x16x32_bf16(vf, ptf, acc_o[dt], 0, 0, 0);
      }
    }
  }

  // epilogue: O = O^T / l. Transpose via wave-private LDS -> coalesced int4 AO stores.
  const float inv = __builtin_amdgcn_rcpf(l_acc[0]);   // all regs equal l[q=lr]
#pragma unroll
  for (int dt = 0; dt < 4; ++dt){
    int2 w;
    w.x = pk2bf(acc_o[dt][0] * inv, acc_o[dt][1] * inv);
    w.y = pk2bf(acc_o[dt][2] * inv, acc_o[dt][3] * inv);
    *(int2*)(Pw + lr*KS_LD + dt*16 + quad*4) = w;      // row q=lr, cols d=16dt+4quad..+3
  }
  // wave-private: compiler inserts lgkmcnt wait before the reads below
#pragma unroll
  for (int i = 0; i < 2; ++i){
    int c = lane + i*64;                 // 128 chunks: 16 q-rows x 8 chunks of 8 shorts
    int row = c >> 3, ch = c & 7;
    int4 v = *(const int4*)(Pw + row*KS_LD + ch*8);
    *(int4*)(AO + (size_t)(bidx*2048 + wq + row)*1024 + h*64 + ch*8) = v;
  }
}

extern "C" void kernel_launch(void* const* d_in, const int* in_sizes, int n_in,
                              void* d_out, int out_size, void* d_ws, size_t ws_size,
                              hipStream_t stream)
{
  const float* x  = (const float*)d_in[0];
  const float* Wq = (const float*)d_in[1];
  const float* bq = (const float*)d_in[2];
  const float* Wk = (const float*)d_in[3];
  const float* bk = (const float*)d_in[4];
  const float* Wv = (const float*)d_in[5];
  const float* bv = (const float*)d_in[6];
  const float* Wp = (const float*)d_in[7];
  const float* bp = (const float*)d_in[8];
  float* out = (float*)d_out;

  char* ws = (char*)d_ws;
  const size_t MB = 1024ull * 1024ull;
  short* Qb  = (short*)(ws + 0);        // [B,H,T,D] bf16 (pre-scaled by log2e/8)
  short* Kb  = (short*)(ws + 8*MB);     // [B,H,T,D] bf16
  short* Vtb = (short*)(ws + 16*MB);    // [B,H,D,T] bf16
  short* AOb = (short*)(ws + 24*MB);    // [B*T, C] bf16 — aliases xb (qkv reads finish first)
  short* xb  = (short*)(ws + 24*MB);    // [M, C] bf16
  short* Wqb = (short*)(ws + 32*MB);
  short* Wkb = (short*)(ws + 34*MB);
  short* Wvb = (short*)(ws + 36*MB);
  short* Wpb = (short*)(ws + 38*MB);

  cvt_all<<<8192, 256, 0, stream>>>(x, Wq, Wk, Wv, Wp, xb, Wqb, Wkb, Wvb, Wpb);
  gemm_qkv<<<dim3(8, 32, 3), 256, 0, stream>>>(xb, Wqb, Wkb, Wvb, bq, bk, bv, Qb, Kb, Vtb);
  attn_kernel<<<1024, 256, 0, stream>>>(Qb, Kb, Vtb, AOb);
  gemm_proj<<<dim3(16, 32), 256, 0, stream>>>(AOb, Wpb, bp, out);
}

// Round 10
// 186.635 us; speedup vs baseline: 1.0517x; 1.0031x over previous
//
#include <hip/hip_runtime.h>
#include <hip/hip_bf16.h>

// B=2, T=2048, C=1024, H=16, D=64, M = B*T = 4096
#define TT 2048
#define MM 4096
#define KS_LD 72   // LDS stride (shorts): 36 dwords, gcd(36,32)=4 -> ~2-way aliasing on staging

typedef __attribute__((ext_vector_type(8))) short bf16x8;
typedef __attribute__((ext_vector_type(4))) float f32x4;

__device__ inline short f2bf(float f){
  union { float f; unsigned u; } x; x.f = f;
  unsigned r = x.u + 0x7FFFu + ((x.u >> 16) & 1u);
  return (short)(r >> 16);
}
__device__ inline int pk2bf(float a, float b){
  __hip_bfloat162 h2 = __float22bfloat162_rn(make_float2(a, b));
  return *(int*)&h2;
}

// async global->LDS, 16B per lane; LDS dest must be wave-uniform base + lane*16
__device__ inline void async16(const void* g, void* l){
  __builtin_amdgcn_global_load_lds((const __attribute__((address_space(1))) void*)g,
                                   (__attribute__((address_space(3))) void*)l, 16, 0, 0);
}

// ---------------- fused fp32 -> bf16 convert (x + 4 weights, one launch) ----------------
__global__ void cvt_all(const float* __restrict__ x,
                        const float* __restrict__ Wq, const float* __restrict__ Wk,
                        const float* __restrict__ Wv, const float* __restrict__ Wp,
                        short* __restrict__ xb, short* __restrict__ Wqb, short* __restrict__ Wkb,
                        short* __restrict__ Wvb, short* __restrict__ Wpb){
  int b = blockIdx.x;
  const float* in; short* out; int base;
  if (b < 4096)      { in = x;  out = xb;  base = b; }
  else if (b < 5120) { in = Wq; out = Wqb; base = b - 4096; }
  else if (b < 6144) { in = Wk; out = Wkb; base = b - 5120; }
  else if (b < 7168) { in = Wv; out = Wvb; base = b - 6144; }
  else               { in = Wp; out = Wpb; base = b - 7168; }
  int i = base * 256 + threadIdx.x;
  float4 v = ((const float4*)in)[i];
  short4 o;
  o.x = f2bf(v.x); o.y = f2bf(v.y); o.z = f2bf(v.z); o.w = f2bf(v.w);
  ((short4*)out)[i] = o;
}

// ---------------- GEMM core: 128x128 tile, BK=64 as two BK=32 panels, async staging ----------------
__device__ inline void gemm_core(const short* __restrict__ A, const short* __restrict__ Wm,
                                 short* As, short* Bs, int m0, int n0,
                                 int tid, int wm, int wn, int quad, int lr,
                                 f32x4 acc[4][4])
{
  const int prow = tid >> 2, pcol = (tid & 3) << 3;
  const short* Ap0 = A  + (size_t)(m0 + prow) * 1024 + pcol;
  const short* Ap1 = A  + (size_t)(m0 + prow + 64) * 1024 + pcol;
  const short* Bp0 = Wm + (size_t)(n0 + prow) * 1024 + pcol;
  const short* Bp1 = Wm + (size_t)(n0 + prow + 64) * 1024 + pcol;
  for (int kt = 0; kt < 16; ++kt){
    const int kk = kt * 64;
#pragma unroll
    for (int pn = 0; pn < 2; ++pn){
      async16(Ap0 + kk + pn*32, As + pn*4096 + (size_t)tid * 8);
      async16(Ap1 + kk + pn*32, As + pn*4096 + (size_t)(tid + 256) * 8);
      async16(Bp0 + kk + pn*32, Bs + pn*4096 + (size_t)tid * 8);
      async16(Bp1 + kk + pn*32, Bs + pn*4096 + (size_t)(tid + 256) * 8);
    }
    __syncthreads();
#pragma unroll
    for (int ks = 0; ks < 2; ++ks){
      bf16x8 aF[4], bF[4];
#pragma unroll
      for (int mt = 0; mt < 4; ++mt) aF[mt] = *(const bf16x8*)(As + ks*4096 + (wm*64 + mt*16 + lr)*32 + quad*8);
#pragma unroll
      for (int nt = 0; nt < 4; ++nt) bF[nt] = *(const bf16x8*)(Bs + ks*4096 + (wn*64 + nt*16 + lr)*32 + quad*8);
#pragma unroll
      for (int mt = 0; mt < 4; ++mt)
#pragma unroll
        for (int nt = 0; nt < 4; ++nt)
          acc[mt][nt] = __builtin_amdgcn_mfma_f32_16x16x32_bf16(aF[mt], bF[nt], acc[mt][nt], 0, 0, 0);
    }
    __syncthreads();
  }
}

// ---------------- QKV projection: Q,K as [B,H,T,D] (Q pre-scaled), V as [B,H,D,T] ----------------
__launch_bounds__(256, 3)
__global__ void gemm_qkv(const short* __restrict__ A,
                         const short* __restrict__ W0, const short* __restrict__ W1, const short* __restrict__ W2,
                         const float* __restrict__ b0, const float* __restrict__ b1, const float* __restrict__ b2,
                         short* __restrict__ Qo, short* __restrict__ Ko, short* __restrict__ Vt)
{
  __shared__ __align__(16) short smem[16384];
  short* As = smem;
  short* Bs = smem + 8192;
  const int z = blockIdx.z;
  const short* Wm   = (z == 0) ? W0 : ((z == 1) ? W1 : W2);
  const float* bias = (z == 0) ? b0 : ((z == 1) ? b1 : b2);
  const int tid = threadIdx.x;
  const int lane = tid & 63, wave = tid >> 6;
  const int wm = wave >> 1, wn = wave & 1;
  const int quad = lane >> 4, lr = lane & 15;
  const int m0 = blockIdx.y * 128, n0 = blockIdx.x * 128;

  f32x4 acc[4][4];
#pragma unroll
  for (int i = 0; i < 4; ++i)
#pragma unroll
    for (int j = 0; j < 4; ++j)
#pragma unroll
      for (int r = 0; r < 4; ++r) acc[i][j][r] = 0.f;

  gemm_core(A, Wm, As, Bs, m0, n0, tid, wm, wn, quad, lr, acc);

  const float qscale = 0.125f * 1.4426950408889634f;  // scale/sqrt(D) * log2(e) folded into Q
  const int bB = m0 >> 11, t0 = m0 & 2047;

  if (z == 2){
    // V: transpose in LDS -> coalesced [B,H,D,T] stores
#pragma unroll
    for (int nh = 0; nh < 2; ++nh){
      __syncthreads();
      if (wn == nh){
#pragma unroll
        for (int nt = 0; nt < 4; ++nt){
          int n = n0 + wn*64 + nt*16 + lr;
          float bv = bias[n];
          int n_l = nt*16 + lr;
#pragma unroll
          for (int mt = 0; mt < 4; ++mt)
#pragma unroll
            for (int r = 0; r < 4; ++r){
              int m_l = wm*64 + mt*16 + quad*4 + r;
              smem[n_l*136 + m_l] = f2bf(acc[mt][nt][r] + bv);
            }
        }
      }
      __syncthreads();
#pragma unroll
      for (int i = 0; i < 4; ++i){
        int c = tid + i*256;
        int rowN = c >> 4, ch = c & 15;
        int4 v = *(const int4*)(smem + rowN*136 + ch*8);
        int n = n0 + nh*64 + rowN;
        int hH = n >> 6, d = n & 63;
        *(int4*)(Vt + ((size_t)((bB<<4) + hH)*64 + d)*2048 + t0 + ch*8) = v;
      }
    }
    return;
  }

  // Q/K: stage [m][n] tile half-by-half in LDS (stride 72), then coalesced int4 row stores
  short* dst = (z == 0) ? Qo : Ko;
#pragma unroll
  for (int nh = 0; nh < 2; ++nh){
    __syncthreads();
    if (wn == nh){
#pragma unroll
      for (int nt = 0; nt < 4; ++nt){
        int n_l = nt*16 + lr;
        float bv = bias[n0 + nh*64 + n_l];
#pragma unroll
        for (int mt = 0; mt < 4; ++mt){
#pragma unroll
          for (int r = 0; r < 4; ++r){
            int m_l = wm*64 + mt*16 + quad*4 + r;
            float v = acc[mt][nt][r] + bv;
            if (z == 0) v *= qscale;
            smem[m_l*72 + n_l] = f2bf(v);
          }
        }
      }
    }
    __syncthreads();
    const int hH = (n0 + nh*64) >> 6;
    short* dhead = dst + (size_t)((bB<<4) + hH) * 2048 * 64;
#pragma unroll
    for (int i = 0; i < 4; ++i){
      int c = tid + i*256;
      int rowm = c >> 3, ch = (c & 7) << 3;
      int4 v = *(const int4*)(smem + rowm*72 + ch);
      *(int4*)(dhead + (size_t)(t0 + rowm)*64 + ch) = v;
    }
  }
}

// ---------------- output projection: 128x64 tiles, BK=64 two-panel ----------------
__launch_bounds__(256, 2)
__global__ void gemm_proj(const short* __restrict__ A, const short* __restrict__ Wm,
                          const float* __restrict__ bias, float* __restrict__ out)
{
  __shared__ __align__(16) short As[2*4096];
  __shared__ __align__(16) short Bs[2*2048];
  const int tid = threadIdx.x;
  const int lane = tid & 63, wave = tid >> 6;
  const int quad = lane >> 4, lr = lane & 15;
  const int m0 = blockIdx.y * 128, n0 = blockIdx.x * 64;

  const int prow = tid >> 2, pcol = (tid & 3) << 3;
  const short* Ap0 = A  + (size_t)(m0 + prow) * 1024 + pcol;
  const short* Ap1 = A  + (size_t)(m0 + prow + 64) * 1024 + pcol;
  const short* Bp0 = Wm + (size_t)(n0 + (tid >> 2)) * 1024 + pcol;

  f32x4 acc[2][4];
#pragma unroll
  for (int i = 0; i < 2; ++i)
#pragma unroll
    for (int j = 0; j < 4; ++j)
#pragma unroll
      for (int r = 0; r < 4; ++r) acc[i][j][r] = 0.f;

  for (int kt = 0; kt < 16; ++kt){
    const int kk = kt * 64;
#pragma unroll
    for (int pn = 0; pn < 2; ++pn){
      async16(Ap0 + kk + pn*32, As + pn*4096 + (size_t)tid * 8);
      async16(Ap1 + kk + pn*32, As + pn*4096 + (size_t)(tid + 256) * 8);
      async16(Bp0 + kk + pn*32, Bs + pn*2048 + (size_t)tid * 8);
    }
    __syncthreads();
#pragma unroll
    for (int ks = 0; ks < 2; ++ks){
      bf16x8 aF[2], bF[4];
#pragma unroll
      for (int mt = 0; mt < 2; ++mt) aF[mt] = *(const bf16x8*)(As + ks*4096 + (wave*32 + mt*16 + lr)*32 + quad*8);
#pragma unroll
      for (int nt = 0; nt < 4; ++nt) bF[nt] = *(const bf16x8*)(Bs + ks*2048 + (nt*16 + lr)*32 + quad*8);
#pragma unroll
      for (int mt = 0; mt < 2; ++mt)
#pragma unroll
        for (int nt = 0; nt < 4; ++nt)
          acc[mt][nt] = __builtin_amdgcn_mfma_f32_16x16x32_bf16(aF[mt], bF[nt], acc[mt][nt], 0, 0, 0);
    }
    __syncthreads();
  }

#pragma unroll
  for (int nt = 0; nt < 4; ++nt){
    int n = n0 + nt*16 + lr;
    float bv = bias[n];
#pragma unroll
    for (int mt = 0; mt < 2; ++mt){
      int mBase = m0 + wave*32 + mt*16 + quad*4;
#pragma unroll
      for (int r = 0; r < 4; ++r){
        int m = mBase + r;
        out[(size_t)m * 1024 + n] = acc[mt][nt][r] + bv;
      }
    }
  }
}

// ---------------- flash attention (causal): S^T formulation + balanced qt->CU mapping ----------------
// Q (pre-scaled by log2e/8), K: [B*H, T, 64] bf16 ; Vt: [B*H, 64, T] bf16 ; AO: [B*T, 1024] bf16
// Grid 1024 = 4 chunks x 8 slices x 32 heads, 4 blocks/CU, one residency round.
// qt per (chunk, a): {31-a, a, 23-a, 8+a} -> per-CU tile-units = (32-a)+(a+1)+(24-a)+(a+9) = 66
// for EVERY slice a (was 80-4a, max 80): uniform makespan. Heavy chunk dispatched first.
__launch_bounds__(256, 4)
__global__ void attn_kernel(const short* __restrict__ Q, const short* __restrict__ K,
                            const short* __restrict__ Vt, short* __restrict__ AO)
{
  __shared__ __align__(16) short Ks[64*KS_LD];
  __shared__ __align__(16) short Vs[64*KS_LD];
  __shared__ __align__(16) short Ps[4*16*KS_LD];   // per-wave P^T/O^T scratch: [16 q][64+8]
  const int tid = threadIdx.x, lane = tid & 63, wave = tid >> 6;
  const int quad = lane >> 4, lr = lane & 15;
  const int bid = blockIdx.x;
  const int chunk = bid >> 8;          // 0..3 (dispatch order: heavy first)
  const int a = (bid >> 5) & 7;        // CU slice 0..7
  int qt;
  if      (chunk == 0) qt = 31 - a;    // 32..24 tiles
  else if (chunk == 1) qt = a;         //  1..8
  else if (chunk == 2) qt = 23 - a;    // 24..17
  else                 qt = 8 + a;     //  9..16   => per-slice sum = 66 for all a
  const int hb = bid & 31;
  const int bidx = hb >> 4, h = hb & 15;
  const int q0 = qt * 64;
  const int wq = q0 + wave * 16;       // this wave's 16 q-rows
  const short* Qh = Q  + (size_t)hb * TT * 64;
  const short* Kh = K  + (size_t)hb * TT * 64;
  const short* Vh = Vt + (size_t)hb * 64 * TT;
  short* Pw = Ps + wave * 16 * KS_LD;

  // loop-invariant Q fragments (used as B-operand: B[k][n=lr=q] = Q[q][k], same lane mapping)
  bf16x8 qf[2];
#pragma unroll
  for (int ks = 0; ks < 2; ++ks)
    qf[ks] = *(const bf16x8*)(Qh + (size_t)(wq + lr) * 64 + ks*32 + quad*8);

  // O^T accumulators: acc_o[dt] holds O[d=16dt+4quad+r][q=lr]; l_acc regs all = l[q=lr]
  f32x4 acc_o[4], l_acc;
#pragma unroll
  for (int r = 0; r < 4; ++r) l_acc[r] = 0.f;
#pragma unroll
  for (int dt = 0; dt < 4; ++dt)
#pragma unroll
    for (int r = 0; r < 4; ++r) acc_o[dt][r] = 0.f;

  const short one_bf = (short)0x3F80;
  const bf16x8 onesf = { one_bf, one_bf, one_bf, one_bf, one_bf, one_bf, one_bf, one_bf };

  // staging geometry: 512 int4 per matrix per tile; chunk c = tid and tid+256 (row+32)
  const int srow = tid >> 3, scol = (tid & 7) << 3;

  const int nkv = qt + 1;
  for (int kv = 0; kv < nkv; ++kv){
    const int kv0 = kv * 64;
    __syncthreads();                       // previous tile's consumers done
#pragma unroll
    for (int s = 0; s < 2; ++s){
      *(int4*)(Ks + (srow + s*32) * KS_LD + scol) = *(const int4*)(Kh + (size_t)(kv0 + srow + s*32) * 64 + scol);
      *(int4*)(Vs + (srow + s*32) * KS_LD + scol) = *(const int4*)(Vh + (size_t)(srow + s*32) * TT + kv0 + scol);
    }
    __syncthreads();
    if (kv0 > wq + 15) continue;           // this wave's rows fully masked

    // S^T = K Q^T: C-layout col = q = lr, row = key = 16nt + 4quad + r
    f32x4 s4[4];
#pragma unroll
    for (int nt = 0; nt < 4; ++nt)
#pragma unroll
      for (int r = 0; r < 4; ++r) s4[nt][r] = 0.f;
#pragma unroll
    for (int nt = 0; nt < 4; ++nt)
#pragma unroll
      for (int ks = 0; ks < 2; ++ks){
        bf16x8 kf = *(const bf16x8*)(Ks + (nt*16 + lr)*KS_LD + ks*32 + quad*8);
        s4[nt] = __builtin_amdgcn_mfma_f32_16x16x32_bf16(kf, qf[ks], s4[nt], 0, 0, 0);
      }

    // P^T = exp2(S^T), mask key > q on the diagonal tile; pack 4 keys -> one b64 store per nt
    const bool need_mask = (kv == nkv - 1);
    const int qglob = wq + lr;
#pragma unroll
    for (int nt = 0; nt < 4; ++nt){
      const int keyb = kv0 + nt*16 + quad*4;
      float pv[4];
#pragma unroll
      for (int r = 0; r < 4; ++r){
        float v = exp2f(s4[nt][r]);
        if (need_mask && keyb + r > qglob) v = 0.f;
        pv[r] = v;
      }
      int2 w;
      w.x = pk2bf(pv[0], pv[1]);
      w.y = pk2bf(pv[2], pv[3]);
      *(int2*)(Pw + lr*KS_LD + nt*16 + quad*4) = w;
    }
    // wave-private Pw: lgkmcnt ordering only, no barrier

    // l += 1^T P^T ; O^T += V^T P^T   (B-frag = P^T rows q=lr, keys 32ks+8quad+j)
#pragma unroll
    for (int ks = 0; ks < 2; ++ks){
      bf16x8 ptf = *(const bf16x8*)(Pw + lr*KS_LD + ks*32 + quad*8);
      l_acc = __builtin_amdgcn_mfma_f32_16x16x32_bf16(onesf, ptf, l_acc, 0, 0, 0);
#pragma unroll
      for (int dt = 0; dt < 4; ++dt){
        bf16x8 vf = *(const bf16x8*)(Vs + (dt*16 + lr)*KS_LD + ks*32 + quad*8);
        acc_o[dt] = __builtin_amdgcn_mfma_f32_16x16x32_bf16(vf, ptf, acc_o[dt], 0, 0, 0);
      }
    }
  }

  // epilogue: O = O^T / l. Transpose via wave-private LDS -> coalesced int4 AO stores.
  const float inv = __builtin_amdgcn_rcpf(l_acc[0]);   // all regs equal l[q=lr]
#pragma unroll
  for (int dt = 0; dt < 4; ++dt){
    int2 w;
    w.x = pk2bf(acc_o[dt][0] * inv, acc_o[dt][1] * inv);
    w.y = pk2bf(acc_o[dt][2] * inv, acc_o[dt][3] * inv);
    *(int2*)(Pw + lr*KS_LD + dt*16 + quad*4) = w;      // row q=lr, cols d=16dt+4quad..+3
  }
  // wave-private: compiler inserts lgkmcnt wait before the reads below
#pragma unroll
  for (int i = 0; i < 2; ++i){
    int c = lane + i*64;                 // 128 chunks: 16 q-rows x 8 chunks of 8 shorts
    int row = c >> 3, ch = c & 7;
    int4 v = *(const int4*)(Pw + row*KS_LD + ch*8);
    *(int4*)(AO + (size_t)(bidx*2048 + wq + row)*1024 + h*64 + ch*8) = v;
  }
}

extern "C" void kernel_launch(void* const* d_in, const int* in_sizes, int n_in,
                              void* d_out, int out_size, void* d_ws, size_t ws_size,
                              hipStream_t stream)
{
  const float* x  = (const float*)d_in[0];
  const float* Wq = (const float*)d_in[1];
  const float* bq = (const float*)d_in[2];
  const float* Wk = (const float*)d_in[3];
  const float* bk = (const float*)d_in[4];
  const float* Wv = (const float*)d_in[5];
  const float* bv = (const float*)d_in[6];
  const float* Wp = (const float*)d_in[7];
  const float* bp = (const float*)d_in[8];
  float* out = (float*)d_out;

  char* ws = (char*)d_ws;
  const size_t MB = 1024ull * 1024ull;
  short* Qb  = (short*)(ws + 0);        // [B,H,T,D] bf16 (pre-scaled by log2e/8)
  short* Kb  = (short*)(ws + 8*MB);     // [B,H,T,D] bf16
  short* Vtb = (short*)(ws + 16*MB);    // [B,H,D,T] bf16
  short* AOb = (short*)(ws + 24*MB);    // [B*T, C] bf16 — aliases xb (qkv reads finish first)
  short* xb  = (short*)(ws + 24*MB);    // [M, C] bf16
  short* Wqb = (short*)(ws + 32*MB);
  short* Wkb = (short*)(ws + 34*MB);
  short* Wvb = (short*)(ws + 36*MB);
  short* Wpb = (short*)(ws + 38*MB);

  cvt_all<<<8192, 256, 0, stream>>>(x, Wq, Wk, Wv, Wp, xb, Wqb, Wkb, Wvb, Wpb);
  gemm_qkv<<<dim3(8, 32, 3), 256, 0, stream>>>(xb, Wqb, Wkb, Wvb, bq, bk, bv, Qb, Kb, Vtb);
  attn_kernel<<<1024, 256, 0, stream>>>(Qb, Kb, Vtb, AOb);
  gemm_proj<<<dim3(16, 32), 256, 0, stream>>>(AOb, Wpb, bp, out);
}

// Round 11
// 180.458 us; speedup vs baseline: 1.0877x; 1.0342x over previous
//
#include <hip/hip_runtime.h>
#include <hip/hip_bf16.h>

// B=2, T=2048, C=1024, H=16, D=64, M = B*T = 4096
#define TT 2048
#define MM 4096

typedef __attribute__((ext_vector_type(8))) short bf16x8;
typedef __attribute__((ext_vector_type(4))) float f32x4;

__device__ inline short f2bf(float f){
  union { float f; unsigned u; } x; x.f = f;
  unsigned r = x.u + 0x7FFFu + ((x.u >> 16) & 1u);
  return (short)(r >> 16);
}
__device__ inline int pk2bf(float a, float b){
  __hip_bfloat162 h2 = __float22bfloat162_rn(make_float2(a, b));
  return *(int*)&h2;
}

// async global->LDS, 16B per lane; LDS dest must be wave-uniform base + lane*16
__device__ inline void async16(const void* g, void* l){
  __builtin_amdgcn_global_load_lds((const __attribute__((address_space(1))) void*)g,
                                   (__attribute__((address_space(3))) void*)l, 16, 0, 0);
}

// ---------------- fused fp32 -> bf16 convert (x + 4 weights, one launch) ----------------
__global__ void cvt_all(const float* __restrict__ x,
                        const float* __restrict__ Wq, const float* __restrict__ Wk,
                        const float* __restrict__ Wv, const float* __restrict__ Wp,
                        short* __restrict__ xb, short* __restrict__ Wqb, short* __restrict__ Wkb,
                        short* __restrict__ Wvb, short* __restrict__ Wpb){
  int b = blockIdx.x;
  const float* in; short* out; int base;
  if (b < 4096)      { in = x;  out = xb;  base = b; }
  else if (b < 5120) { in = Wq; out = Wqb; base = b - 4096; }
  else if (b < 6144) { in = Wk; out = Wkb; base = b - 5120; }
  else if (b < 7168) { in = Wv; out = Wvb; base = b - 6144; }
  else               { in = Wp; out = Wpb; base = b - 7168; }
  int i = base * 256 + threadIdx.x;
  float4 v = ((const float4*)in)[i];
  short4 o;
  o.x = f2bf(v.x); o.y = f2bf(v.y); o.z = f2bf(v.z); o.w = f2bf(v.w);
  ((short4*)out)[i] = o;
}

// ---------------- GEMM core: 128x128 tile, BK=64 as two BK=32 panels, async staging ----------------
__device__ inline void gemm_core(const short* __restrict__ A, const short* __restrict__ Wm,
                                 short* As, short* Bs, int m0, int n0,
                                 int tid, int wm, int wn, int quad, int lr,
                                 f32x4 acc[4][4])
{
  const int prow = tid >> 2, pcol = (tid & 3) << 3;
  const short* Ap0 = A  + (size_t)(m0 + prow) * 1024 + pcol;
  const short* Ap1 = A  + (size_t)(m0 + prow + 64) * 1024 + pcol;
  const short* Bp0 = Wm + (size_t)(n0 + prow) * 1024 + pcol;
  const short* Bp1 = Wm + (size_t)(n0 + prow + 64) * 1024 + pcol;
  for (int kt = 0; kt < 16; ++kt){
    const int kk = kt * 64;
#pragma unroll
    for (int pn = 0; pn < 2; ++pn){
      async16(Ap0 + kk + pn*32, As + pn*4096 + (size_t)tid * 8);
      async16(Ap1 + kk + pn*32, As + pn*4096 + (size_t)(tid + 256) * 8);
      async16(Bp0 + kk + pn*32, Bs + pn*4096 + (size_t)tid * 8);
      async16(Bp1 + kk + pn*32, Bs + pn*4096 + (size_t)(tid + 256) * 8);
    }
    __syncthreads();
#pragma unroll
    for (int ks = 0; ks < 2; ++ks){
      bf16x8 aF[4], bF[4];
#pragma unroll
      for (int mt = 0; mt < 4; ++mt) aF[mt] = *(const bf16x8*)(As + ks*4096 + (wm*64 + mt*16 + lr)*32 + quad*8);
#pragma unroll
      for (int nt = 0; nt < 4; ++nt) bF[nt] = *(const bf16x8*)(Bs + ks*4096 + (wn*64 + nt*16 + lr)*32 + quad*8);
#pragma unroll
      for (int mt = 0; mt < 4; ++mt)
#pragma unroll
        for (int nt = 0; nt < 4; ++nt)
          acc[mt][nt] = __builtin_amdgcn_mfma_f32_16x16x32_bf16(aF[mt], bF[nt], acc[mt][nt], 0, 0, 0);
    }
    __syncthreads();
  }
}

// ---------------- QKV projection: Q,K as [B,H,T,D] (Q pre-scaled), V as [B,H,D,T] ----------------
__launch_bounds__(256, 3)
__global__ void gemm_qkv(const short* __restrict__ A,
                         const short* __restrict__ W0, const short* __restrict__ W1, const short* __restrict__ W2,
                         const float* __restrict__ b0, const float* __restrict__ b1, const float* __restrict__ b2,
                         short* __restrict__ Qo, short* __restrict__ Ko, short* __restrict__ Vt)
{
  __shared__ __align__(16) short smem[16384];
  short* As = smem;
  short* Bs = smem + 8192;
  const int z = blockIdx.z;
  const short* Wm   = (z == 0) ? W0 : ((z == 1) ? W1 : W2);
  const float* bias = (z == 0) ? b0 : ((z == 1) ? b1 : b2);
  const int tid = threadIdx.x;
  const int lane = tid & 63, wave = tid >> 6;
  const int wm = wave >> 1, wn = wave & 1;
  const int quad = lane >> 4, lr = lane & 15;
  const int m0 = blockIdx.y * 128, n0 = blockIdx.x * 128;

  f32x4 acc[4][4];
#pragma unroll
  for (int i = 0; i < 4; ++i)
#pragma unroll
    for (int j = 0; j < 4; ++j)
#pragma unroll
      for (int r = 0; r < 4; ++r) acc[i][j][r] = 0.f;

  gemm_core(A, Wm, As, Bs, m0, n0, tid, wm, wn, quad, lr, acc);

  const float qscale = 0.125f * 1.4426950408889634f;  // scale/sqrt(D) * log2(e) folded into Q
  const int bB = m0 >> 11, t0 = m0 & 2047;

  if (z == 2){
    // V: transpose in LDS -> coalesced [B,H,D,T] stores
#pragma unroll
    for (int nh = 0; nh < 2; ++nh){
      __syncthreads();
      if (wn == nh){
#pragma unroll
        for (int nt = 0; nt < 4; ++nt){
          int n = n0 + wn*64 + nt*16 + lr;
          float bv = bias[n];
          int n_l = nt*16 + lr;
#pragma unroll
          for (int mt = 0; mt < 4; ++mt)
#pragma unroll
            for (int r = 0; r < 4; ++r){
              int m_l = wm*64 + mt*16 + quad*4 + r;
              smem[n_l*136 + m_l] = f2bf(acc[mt][nt][r] + bv);
            }
        }
      }
      __syncthreads();
#pragma unroll
      for (int i = 0; i < 4; ++i){
        int c = tid + i*256;
        int rowN = c >> 4, ch = c & 15;
        int4 v = *(const int4*)(smem + rowN*136 + ch*8);
        int n = n0 + nh*64 + rowN;
        int hH = n >> 6, d = n & 63;
        *(int4*)(Vt + ((size_t)((bB<<4) + hH)*64 + d)*2048 + t0 + ch*8) = v;
      }
    }
    return;
  }

  // Q/K: stage [m][n] tile half-by-half in LDS (stride 72), then coalesced int4 row stores
  short* dst = (z == 0) ? Qo : Ko;
#pragma unroll
  for (int nh = 0; nh < 2; ++nh){
    __syncthreads();
    if (wn == nh){
#pragma unroll
      for (int nt = 0; nt < 4; ++nt){
        int n_l = nt*16 + lr;
        float bv = bias[n0 + nh*64 + n_l];
#pragma unroll
        for (int mt = 0; mt < 4; ++mt){
#pragma unroll
          for (int r = 0; r < 4; ++r){
            int m_l = wm*64 + mt*16 + quad*4 + r;
            float v = acc[mt][nt][r] + bv;
            if (z == 0) v *= qscale;
            smem[m_l*72 + n_l] = f2bf(v);
          }
        }
      }
    }
    __syncthreads();
    const int hH = (n0 + nh*64) >> 6;
    short* dhead = dst + (size_t)((bB<<4) + hH) * 2048 * 64;
#pragma unroll
    for (int i = 0; i < 4; ++i){
      int c = tid + i*256;
      int rowm = c >> 3, ch = (c & 7) << 3;
      int4 v = *(const int4*)(smem + rowm*72 + ch);
      *(int4*)(dhead + (size_t)(t0 + rowm)*64 + ch) = v;
    }
  }
}

// ---------------- output projection: 128x64 tiles, BK=64 two-panel ----------------
__launch_bounds__(256, 2)
__global__ void gemm_proj(const short* __restrict__ A, const short* __restrict__ Wm,
                          const float* __restrict__ bias, float* __restrict__ out)
{
  __shared__ __align__(16) short As[2*4096];
  __shared__ __align__(16) short Bs[2*2048];
  const int tid = threadIdx.x;
  const int lane = tid & 63, wave = tid >> 6;
  const int quad = lane >> 4, lr = lane & 15;
  const int m0 = blockIdx.y * 128, n0 = blockIdx.x * 64;

  const int prow = tid >> 2, pcol = (tid & 3) << 3;
  const short* Ap0 = A  + (size_t)(m0 + prow) * 1024 + pcol;
  const short* Ap1 = A  + (size_t)(m0 + prow + 64) * 1024 + pcol;
  const short* Bp0 = Wm + (size_t)(n0 + (tid >> 2)) * 1024 + pcol;

  f32x4 acc[2][4];
#pragma unroll
  for (int i = 0; i < 2; ++i)
#pragma unroll
    for (int j = 0; j < 4; ++j)
#pragma unroll
      for (int r = 0; r < 4; ++r) acc[i][j][r] = 0.f;

  for (int kt = 0; kt < 16; ++kt){
    const int kk = kt * 64;
#pragma unroll
    for (int pn = 0; pn < 2; ++pn){
      async16(Ap0 + kk + pn*32, As + pn*4096 + (size_t)tid * 8);
      async16(Ap1 + kk + pn*32, As + pn*4096 + (size_t)(tid + 256) * 8);
      async16(Bp0 + kk + pn*32, Bs + pn*2048 + (size_t)tid * 8);
    }
    __syncthreads();
#pragma unroll
    for (int ks = 0; ks < 2; ++ks){
      bf16x8 aF[2], bF[4];
#pragma unroll
      for (int mt = 0; mt < 2; ++mt) aF[mt] = *(const bf16x8*)(As + ks*4096 + (wave*32 + mt*16 + lr)*32 + quad*8);
#pragma unroll
      for (int nt = 0; nt < 4; ++nt) bF[nt] = *(const bf16x8*)(Bs + ks*2048 + (nt*16 + lr)*32 + quad*8);
#pragma unroll
      for (int mt = 0; mt < 2; ++mt)
#pragma unroll
        for (int nt = 0; nt < 4; ++nt)
          acc[mt][nt] = __builtin_amdgcn_mfma_f32_16x16x32_bf16(aF[mt], bF[nt], acc[mt][nt], 0, 0, 0);
    }
    __syncthreads();
  }

#pragma unroll
  for (int nt = 0; nt < 4; ++nt){
    int n = n0 + nt*16 + lr;
    float bv = bias[n];
#pragma unroll
    for (int mt = 0; mt < 2; ++mt){
      int mBase = m0 + wave*32 + mt*16 + quad*4;
#pragma unroll
      for (int r = 0; r < 4; ++r){
        int m = mBase + r;
        out[(size_t)m * 1024 + n] = acc[mt][nt][r] + bv;
      }
    }
  }
}

// ---------------- flash attention (causal): single-barrier dbuf pipeline, swizzled LDS ----------------
// Q (pre-scaled by log2e/8), K: [B*H, T, 64] bf16 ; Vt: [B*H, 64, T] bf16 ; AO: [B*T, 1024] bf16
// Grid 1024 = 4 chunks x 8 slices x 32 heads (balanced qt: per-CU sum = 66), 4 blocks/CU (LDS = 40960 B
// exactly -> 160 KiB). K/V staged via global_load_lds into UNPADDED double buffers with an XOR swizzle
// (chunk' = chunk ^ (row&7)) baked into the per-lane SOURCE address: LDS writes lane-contiguous
// (conflict-free), frag reads 2-way aliased (free). One __syncthreads per tile: stage of tile k+1 is
// issued right after the barrier and its latency hides under tile k's compute (drained by next barrier).
__launch_bounds__(256, 4)
__global__ void attn_kernel(const short* __restrict__ Q, const short* __restrict__ K,
                            const short* __restrict__ Vt, short* __restrict__ AO)
{
  __shared__ __align__(16) short Ks[2][4096];   // [buf][64 rows x 64 shorts], swizzled
  __shared__ __align__(16) short Vs[2][4096];
  __shared__ __align__(16) short Ps[4096];      // per-wave 16x64 P^T/O^T scratch, swizzled
  const int tid = threadIdx.x, lane = tid & 63, wave = tid >> 6;
  const int quad = lane >> 4, lr = lane & 15;
  const int bid = blockIdx.x;
  const int chunk = bid >> 8;          // 0..3 (dispatch order: heavy first)
  const int a = (bid >> 5) & 7;        // CU slice 0..7
  int qt;
  if      (chunk == 0) qt = 31 - a;
  else if (chunk == 1) qt = a;
  else if (chunk == 2) qt = 23 - a;
  else                 qt = 8 + a;     // per-slice tile-unit sum = 66 for all a
  const int hb = bid & 31;
  const int bidx = hb >> 4, h = hb & 15;
  const int q0 = qt * 64;
  const int wq = q0 + wave * 16;       // this wave's 16 q-rows
  const short* Qh = Q  + (size_t)hb * TT * 64;
  const short* Kh = K  + (size_t)hb * TT * 64;
  const short* Vh = Vt + (size_t)hb * 64 * TT;
  short* Pw = Ps + wave * 1024;

  // staging: chunk c = tid covers (row = c>>3, swizzled col-chunk); c+256 = row+32, same swizzle
  const int srow = tid >> 3;
  const int ssw  = (tid & 7) ^ (srow & 7);
  const short* Kp0 = Kh + (size_t)srow * 64 + ssw * 8;
  const short* Vp0 = Vh + (size_t)srow * TT + ssw * 8;

  // loop-invariant Q fragments (B-operand: n = lr = q)
  bf16x8 qf[2];
#pragma unroll
  for (int ks = 0; ks < 2; ++ks)
    qf[ks] = *(const bf16x8*)(Qh + (size_t)(wq + lr) * 64 + ks*32 + quad*8);

  // swizzled frag-read chunk offsets (loop-invariant): chunk ks*4+quad, row-phase lr&7
  const int lsw0 = (((0*4 + quad) ^ (lr & 7)) << 3);
  const int lsw1 = (((1*4 + quad) ^ (lr & 7)) << 3);
  const int qh2 = quad >> 1, qlo = (quad & 1) << 2;

  f32x4 acc_o[4], l_acc;
#pragma unroll
  for (int r = 0; r < 4; ++r) l_acc[r] = 0.f;
#pragma unroll
  for (int dt = 0; dt < 4; ++dt)
#pragma unroll
    for (int r = 0; r < 4; ++r) acc_o[dt][r] = 0.f;

  const short one_bf = (short)0x3F80;
  const bf16x8 onesf = { one_bf, one_bf, one_bf, one_bf, one_bf, one_bf, one_bf, one_bf };

  const int nkv = qt + 1;
  // prologue: stage tile 0 into buffer 0 (async)
  async16(Kp0,           &Ks[0][(size_t)tid * 8]);
  async16(Kp0 + 32*64,   &Ks[0][(size_t)(tid + 256) * 8]);
  async16(Vp0,           &Vs[0][(size_t)tid * 8]);
  async16(Vp0 + 32*TT,   &Vs[0][(size_t)(tid + 256) * 8]);

  int cur = 0;
  for (int kv = 0; kv < nkv; ++kv){
    const int kv0 = kv * 64;
    __syncthreads();                     // drains vmcnt: buf[cur] ready; prior reads of buf[cur^1] done
    if (kv + 1 < nkv){                   // async stage tile kv+1 into the other buffer
      const short* kp = Kp0 + (size_t)(kv + 1) * 4096;
      const short* vp = Vp0 + (kv + 1) * 64;
      const int nb = cur ^ 1;
      async16(kp,          &Ks[nb][(size_t)tid * 8]);
      async16(kp + 32*64,  &Ks[nb][(size_t)(tid + 256) * 8]);
      async16(vp,          &Vs[nb][(size_t)tid * 8]);
      async16(vp + 32*TT,  &Vs[nb][(size_t)(tid + 256) * 8]);
    }
    if (kv0 <= wq + 15){
      // S^T = K Q^T: C-layout col = q = lr, row = key = 16nt + 4quad + r
      f32x4 s4[4];
#pragma unroll
      for (int nt = 0; nt < 4; ++nt)
#pragma unroll
        for (int r = 0; r < 4; ++r) s4[nt][r] = 0.f;
#pragma unroll
      for (int nt = 0; nt < 4; ++nt){
        bf16x8 kf0 = *(const bf16x8*)(&Ks[cur][(nt*16 + lr)*64 + lsw0]);
        bf16x8 kf1 = *(const bf16x8*)(&Ks[cur][(nt*16 + lr)*64 + lsw1]);
        s4[nt] = __builtin_amdgcn_mfma_f32_16x16x32_bf16(kf0, qf[0], s4[nt], 0, 0, 0);
        s4[nt] = __builtin_amdgcn_mfma_f32_16x16x32_bf16(kf1, qf[1], s4[nt], 0, 0, 0);
      }

      // P^T = exp2(S^T), mask key > q on the diagonal tile; swizzled b64 stores (2-way, free)
      const bool need_mask = (kv == nkv - 1);
      const int qglob = wq + lr;
#pragma unroll
      for (int nt = 0; nt < 4; ++nt){
        const int keyb = kv0 + nt*16 + quad*4;
        float pv[4];
#pragma unroll
        for (int r = 0; r < 4; ++r){
          float v = exp2f(s4[nt][r]);
          if (need_mask && keyb + r > qglob) v = 0.f;
          pv[r] = v;
        }
        int2 w;
        w.x = pk2bf(pv[0], pv[1]);
        w.y = pk2bf(pv[2], pv[3]);
        const int g = nt*2 + qh2;
        *(int2*)(Pw + lr*64 + ((g ^ (lr & 7)) << 3) + qlo) = w;
      }
      // wave-private Pw: lgkmcnt ordering only, no barrier

      // l += 1^T P^T ; O^T += V^T P^T
#pragma unroll
      for (int ks = 0; ks < 2; ++ks){
        const int lsw = ks ? lsw1 : lsw0;
        bf16x8 ptf = *(const bf16x8*)(Pw + lr*64 + lsw);
        l_acc = __builtin_amdgcn_mfma_f32_16x16x32_bf16(onesf, ptf, l_acc, 0, 0, 0);
#pragma unroll
        for (int dt = 0; dt < 4; ++dt){
          bf16x8 vf = *(const bf16x8*)(&Vs[cur][(dt*16 + lr)*64 + lsw]);
          acc_o[dt] = __builtin_amdgcn_mfma_f32_16x16x32_bf16(vf, ptf, acc_o[dt], 0, 0, 0);
        }
      }
    }
    cur ^= 1;
  }

  // epilogue: O = O^T / l; transpose via swizzled wave-private LDS -> coalesced int4 AO stores
  const float inv = __builtin_amdgcn_rcpf(l_acc[0]);   // all regs equal l[q=lr]
#pragma unroll
  for (int dt = 0; dt < 4; ++dt){
    int2 w;
    w.x = pk2bf(acc_o[dt][0] * inv, acc_o[dt][1] * inv);
    w.y = pk2bf(acc_o[dt][2] * inv, acc_o[dt][3] * inv);
    const int g = dt*2 + qh2;
    *(int2*)(Pw + lr*64 + ((g ^ (lr & 7)) << 3) + qlo) = w;
  }
  // wave-private: compiler inserts lgkmcnt wait before the reads below
#pragma unroll
  for (int i = 0; i < 2; ++i){
    int c = lane + i*64;                 // 128 chunks: 16 q-rows x 8 chunks of 8 shorts
    int row = c >> 3, ch = c & 7;
    int4 v = *(const int4*)(Pw + row*64 + ((ch ^ (row & 7)) << 3));
    *(int4*)(AO + (size_t)(bidx*2048 + wq + row)*1024 + h*64 + ch*8) = v;
  }
}

extern "C" void kernel_launch(void* const* d_in, const int* in_sizes, int n_in,
                              void* d_out, int out_size, void* d_ws, size_t ws_size,
                              hipStream_t stream)
{
  const float* x  = (const float*)d_in[0];
  const float* Wq = (const float*)d_in[1];
  const float* bq = (const float*)d_in[2];
  const float* Wk = (const float*)d_in[3];
  const float* bk = (const float*)d_in[4];
  const float* Wv = (const float*)d_in[5];
  const float* bv = (const float*)d_in[6];
  const float* Wp = (const float*)d_in[7];
  const float* bp = (const float*)d_in[8];
  float* out = (float*)d_out;

  char* ws = (char*)d_ws;
  const size_t MB = 1024ull * 1024ull;
  short* Qb  = (short*)(ws + 0);        // [B,H,T,D] bf16 (pre-scaled by log2e/8)
  short* Kb  = (short*)(ws + 8*MB);     // [B,H,T,D] bf16
  short* Vtb = (short*)(ws + 16*MB);    // [B,H,D,T] bf16
  short* AOb = (short*)(ws + 24*MB);    // [B*T, C] bf16 — aliases xb (qkv reads finish first)
  short* xb  = (short*)(ws + 24*MB);    // [M, C] bf16
  short* Wqb = (short*)(ws + 32*MB);
  short* Wkb = (short*)(ws + 34*MB);
  short* Wvb = (short*)(ws + 36*MB);
  short* Wpb = (short*)(ws + 38*MB);

  cvt_all<<<8192, 256, 0, stream>>>(x, Wq, Wk, Wv, Wp, xb, Wqb, Wkb, Wvb, Wpb);
  gemm_qkv<<<dim3(8, 32, 3), 256, 0, stream>>>(xb, Wqb, Wkb, Wvb, bq, bk, bv, Qb, Kb, Vtb);
  attn_kernel<<<1024, 256, 0, stream>>>(Qb, Kb, Vtb, AOb);
  gemm_proj<<<dim3(16, 32), 256, 0, stream>>>(AOb, Wpb, bp, out);
}